// Round 1
// baseline (744.124 us; speedup 1.0000x reference)
//
#include <hip/hip_runtime.h>

// ConvMlp4d: conv4d(64->128, 3^4, SAME) + bias + relu, then conv4d(128->64) + bias.
// Strategy: channels-last implicit GEMM with bf16 MFMA (threshold is bf16-scale).
//   ws layout:
//     x_t  bf16 [2][65536][64]   (16,777,216 B)
//     h_t  bf16 [2][65536][128]  (33,554,432 B)
//     w1t  bf16 [81][128][64]    ( 1,327,104 B)
//     w2t  bf16 [81][64][128]    ( 1,327,104 B)   total ~53 MB

using bf16x8 = __attribute__((ext_vector_type(8))) __bf16;
using f32x4  = __attribute__((ext_vector_type(4))) float;

// ---------------- prep: x (2,64,65536) f32 -> x_t (2,65536,64) bf16 ----------------
__global__ __launch_bounds__(256) void cvt_x(const float* __restrict__ x,
                                             __bf16* __restrict__ x_t) {
    __shared__ float lt[64][65];
    const int nb = blockIdx.y;
    const int p0 = blockIdx.x * 64;
    const float* src = x + (size_t)nb * 64 * 65536;
    __bf16* dst = x_t + (size_t)nb * 65536 * 64;
    #pragma unroll
    for (int i = 0; i < 16; ++i) {
        int idx = i * 256 + threadIdx.x;      // 0..4095
        int c = idx >> 6, p = idx & 63;
        lt[c][p] = src[(size_t)c * 65536 + p0 + p];
    }
    __syncthreads();
    #pragma unroll
    for (int i = 0; i < 16; ++i) {
        int idx = i * 256 + threadIdx.x;
        int p = idx >> 6, c = idx & 63;
        dst[(size_t)(p0 + p) * 64 + c] = (__bf16)lt[c][p];
    }
}

// ---------------- prep: w (O,I,81) f32 -> wt (81,O,I) bf16; O*I == 8192 ------------
__global__ __launch_bounds__(256) void cvt_w(const float* __restrict__ w,
                                             __bf16* __restrict__ wt) {
    int oc = blockIdx.x * 256 + threadIdx.x;  // 0..8191 == o*CIN + c
    if (oc >= 8192) return;
    const float* src = w + (size_t)oc * 81;
    #pragma unroll 1
    for (int tap = 0; tap < 81; ++tap)
        wt[(size_t)tap * 8192 + oc] = (__bf16)src[tap];
}

// ---------------- fused conv4d (implicit GEMM, bf16 MFMA) --------------------------
// Block: 256 thr (4 waves). Tile: M=128 spatial (4 w-rows @ fixed n,t,u,v0), N=COUT.
// Wave grid 2(m)x2(n): wave = 64 m x 16*NT n  (NT=4 -> conv1 N=128, NT=2 -> conv2 N=64).
// K = 81 taps x CIN, tap-major; per (kt,ku) stage 6x34x(CIN) halo tile in LDS (+8 pad).
// B (weights) read directly from global in frag-contiguous layout wt[tap][o][c].
template <int CIN, int COUT, int NT, bool RELU_BF16_OUT>
__global__ __launch_bounds__(256, 2) void conv4d_mfma(
    const __bf16* __restrict__ in_t,   // [2][65536][CIN] channels-last
    const __bf16* __restrict__ wt,     // [81][COUT][CIN]
    const float* __restrict__ bias,    // [COUT]
    __bf16* __restrict__ out_bf,       // [2][65536][COUT] (if RELU_BF16_OUT)
    float* __restrict__ out_f)         // [2][COUT][65536] (else)
{
    constexpr int CP = CIN + 8;                 // padded c stride (2-way banks: free)
    __shared__ __bf16 tile[6 * 34 * CP];

    const int tid  = threadIdx.x;
    const int lane = tid & 63;
    const int l15  = lane & 15;
    const int quad = lane >> 4;
    const int wv   = tid >> 6;
    const int m_base = (wv >> 1) * 64;
    const int n_base = (wv & 1) * (16 * NT);

    const int bid = blockIdx.x;
    const int vg = bid & 7, u = (bid >> 3) & 15, t = (bid >> 7) & 3, nb = bid >> 9;
    const int v0 = vg * 4;
    const int pbase = ((t * 16 + u) * 32 + v0) * 32;   // linear spatial base (per batch)

    const __bf16* inb = in_t + (size_t)nb * 65536 * CIN;

    f32x4 acc[4][NT];
    #pragma unroll
    for (int mt = 0; mt < 4; ++mt)
        #pragma unroll
        for (int nt = 0; nt < NT; ++nt)
            acc[mt][nt] = f32x4{0.f, 0.f, 0.f, 0.f};

    #pragma unroll 1
    for (int kt = 0; kt < 3; ++kt) {
        const int t_in = t + kt - 1;
        #pragma unroll 1
        for (int ku = 0; ku < 3; ++ku) {
            const int u_in = u + ku - 1;
            const bool vtu = ((unsigned)t_in < 4u) && ((unsigned)u_in < 16u);
            __syncthreads();
            // ---- stage 6 rows x 34 wp x CIN chan into LDS (zero the halo) ----
            {
                constexpr int CH = CIN / 8;            // 16B chunks per wp
                constexpr int NCH = 6 * 34 * CH;
                const int rowbase = (t_in * 16 + u_in) * 1024;   // *32*32
                for (int idx = tid; idx < NCH; idx += 256) {
                    const int cc   = idx % CH;         // pow2
                    const int rest = idx / CH;
                    const int wp   = rest % 34;
                    const int r    = rest / 34;        // 0..5
                    const int v_in = v0 - 1 + r;
                    const int w_in = wp - 1;
                    uint4 val = make_uint4(0u, 0u, 0u, 0u);
                    if (vtu && ((unsigned)v_in < 32u) && ((unsigned)w_in < 32u)) {
                        val = *(const uint4*)(inb +
                              (size_t)(rowbase + v_in * 32 + w_in) * CIN + cc * 8);
                    }
                    *(uint4*)(&tile[(r * 34 + wp) * CP + cc * 8]) = val;
                }
            }
            __syncthreads();
            // ---- K-loop over kv,kw,c-blocks using the staged tile ----
            #pragma unroll 1
            for (int kv = 0; kv < 3; ++kv) {
                const int tap0 = ((kt * 3 + ku) * 3 + kv) * 3;
                #pragma unroll
                for (int kw = 0; kw < 3; ++kw) {
                    const __bf16* wtap = wt + (size_t)(tap0 + kw) * (COUT * CIN);
                    #pragma unroll
                    for (int cb = 0; cb < CIN / 32; ++cb) {
                        bf16x8 af[4];
                        #pragma unroll
                        for (int mt = 0; mt < 4; ++mt) {
                            const int m  = m_base + mt * 16 + l15;  // A: m = lane&15
                            const int vr = (m >> 5) + kv;           // 0..5
                            const int wc = (m & 31) + kw;           // 0..33
                            af[mt] = *(const bf16x8*)(&tile[(vr * 34 + wc) * CP +
                                                            cb * 32 + quad * 8]);
                        }
                        bf16x8 bfr[NT];
                        #pragma unroll
                        for (int nt = 0; nt < NT; ++nt) {
                            const int o = n_base + nt * 16 + l15;   // B: n = lane&15
                            bfr[nt] = *(const bf16x8*)(wtap + (size_t)o * CIN +
                                                       cb * 32 + quad * 8);
                        }
                        #pragma unroll
                        for (int mt = 0; mt < 4; ++mt)
                            #pragma unroll
                            for (int nt = 0; nt < NT; ++nt)
                                acc[mt][nt] = __builtin_amdgcn_mfma_f32_16x16x32_bf16(
                                    af[mt], bfr[nt], acc[mt][nt], 0, 0, 0);
                    }
                }
            }
        }
    }

    // ---- epilogue: bias (+relu+bf16 channels-last) or (fp32 NCTUVW) ----
    #pragma unroll
    for (int nt = 0; nt < NT; ++nt) {
        const int o = n_base + nt * 16 + l15;      // C/D: col = lane&15
        const float bv = bias[o];
        #pragma unroll
        for (int mt = 0; mt < 4; ++mt) {
            const int p0 = pbase + m_base + mt * 16 + quad * 4;  // row = quad*4+reg
            f32x4 v = acc[mt][nt];
            if constexpr (RELU_BF16_OUT) {
                #pragma unroll
                for (int r = 0; r < 4; ++r) {
                    float xr = v[r] + bv;
                    xr = xr > 0.f ? xr : 0.f;
                    out_bf[(size_t)(nb * 65536 + p0 + r) * COUT + o] = (__bf16)xr;
                }
            } else {
                f32x4 s = {v[0] + bv, v[1] + bv, v[2] + bv, v[3] + bv};
                *(f32x4*)(out_f + ((size_t)(nb * COUT + o)) * 65536 + p0) = s;
            }
        }
    }
}

extern "C" void kernel_launch(void* const* d_in, const int* in_sizes, int n_in,
                              void* d_out, int out_size, void* d_ws, size_t ws_size,
                              hipStream_t stream) {
    const float* x  = (const float*)d_in[0];
    const float* w1 = (const float*)d_in[1];
    const float* b1 = (const float*)d_in[2];
    const float* w2 = (const float*)d_in[3];
    const float* b2 = (const float*)d_in[4];
    float* out = (float*)d_out;

    char* ws = (char*)d_ws;
    __bf16* x_t = (__bf16*)ws;                               // 16,777,216 B
    __bf16* h_t = (__bf16*)(ws + 16777216);                  // 33,554,432 B
    __bf16* w1t = (__bf16*)(ws + 16777216 + 33554432);       //  1,327,104 B
    __bf16* w2t = (__bf16*)(ws + 16777216 + 33554432 + 1327104);

    cvt_x<<<dim3(1024, 2), 256, 0, stream>>>(x, x_t);
    cvt_w<<<32, 256, 0, stream>>>(w1, w1t);
    cvt_w<<<32, 256, 0, stream>>>(w2, w2t);

    // conv1: CIN=64, COUT=128, N-tile per wave = 64 (NT=4), relu -> bf16 channels-last
    conv4d_mfma<64, 128, 4, true><<<1024, 256, 0, stream>>>(x_t, w1t, b1, h_t, nullptr);
    // conv2: CIN=128, COUT=64, NT=2, bias -> fp32 NCTUVW output
    conv4d_mfma<128, 64, 2, false><<<1024, 256, 0, stream>>>(h_t, w2t, b2, nullptr, out);
}

// Round 3
// 456.178 us; speedup vs baseline: 1.6312x; 1.6312x over previous
//
#include <hip/hip_runtime.h>

// ConvMlp4d: conv4d(64->128) + bias + relu -> conv4d(128->64) + bias.
// R3 = R2 with the blockIdx decomposition fixed (R2 decoded nb from the wrong
// bits -> OOB access -> GPU memory fault). 32x32x16 MFMA, wave tile 128x64
// (conv1) / 128x32 (conv2), block M=256 (v-span 8), XOR-swizzled 128B LDS rows
// (conflict-free), coalesced weight layout [tap][k16][O][16], block-uniform
// skip of OOB (kt,ku) stages.
//   ws: x_t bf16 [2][65536][64] | h_t bf16 [2][65536][128]
//       w1t bf16 [81][4][128][16] | w2t bf16 [81][8][64][16]

using bf16x8 = __attribute__((ext_vector_type(8))) __bf16;
using f32x16 = __attribute__((ext_vector_type(16))) float;
using f32x4  = __attribute__((ext_vector_type(4))) float;

// ---------------- prep: x (2,64,65536) f32 -> x_t (2,65536,64) bf16 ----------------
__global__ __launch_bounds__(256) void cvt_x(const float* __restrict__ x,
                                             __bf16* __restrict__ x_t) {
    __shared__ float lt[64][65];
    const int nb = blockIdx.y;
    const int p0 = blockIdx.x * 64;
    const float* src = x + (size_t)nb * 64 * 65536;
    __bf16* dst = x_t + (size_t)nb * 65536 * 64;
    #pragma unroll
    for (int i = 0; i < 16; ++i) {
        int idx = i * 256 + threadIdx.x;
        int c = idx >> 6, p = idx & 63;
        lt[c][p] = src[(size_t)c * 65536 + p0 + p];
    }
    __syncthreads();
    #pragma unroll
    for (int i = 0; i < 16; ++i) {
        int idx = i * 256 + threadIdx.x;
        int p = idx >> 6, c = idx & 63;
        dst[(size_t)(p0 + p) * 64 + c] = (__bf16)lt[c][p];
    }
}

// ------- prep: w (O,CIN,81) f32 -> wt [81][CIN/16][COUT][16] bf16 (frag-coalesced) --
template <int CIN>
__global__ __launch_bounds__(256) void cvt_w(const float* __restrict__ w,
                                             __bf16* __restrict__ wt) {
    constexpr int LOG = (CIN == 64) ? 6 : 7;
    constexpr int COUT = 8192 / CIN;
    int oc = blockIdx.x * 256 + threadIdx.x;          // o*CIN + c
    if (oc >= 8192) return;
    const int o = oc >> LOG, c = oc & (CIN - 1);
    const int kg = c >> 4, cl = c & 15;
    const float* src = w + (size_t)oc * 81;
    #pragma unroll 1
    for (int tap = 0; tap < 81; ++tap)
        wt[(((size_t)tap * (CIN / 16) + kg) * COUT + o) * 16 + cl] = (__bf16)src[tap];
}

// ---------------- fused conv4d (implicit GEMM, 32x32x16 bf16 MFMA) -----------------
// Block: 256 thr = 4 waves, wave grid 2(m) x 2(n). Block tile: M=256 spatial
// (v-span 8 at fixed n,t,u), N = 2*NT*32. Wave tile: M=128 (MT=4), N = NT*32.
// Per (kt,ku[,chalf]) stage: 10x34 halo rows x 64ch in LDS, rows = 128B,
// chunk XOR-swizzle by (pos&7) -> conflict-free ds_read_b128 / ds_write_b128.
template <int CIN, int COUT, int MT, int NT, int CHALVES, bool RELU>
__global__ __launch_bounds__(256, 2) void conv4d_mfma(
    const __bf16* __restrict__ in_t,   // [2][65536][CIN] channels-last
    const __bf16* __restrict__ wt,     // [81][CIN/16][COUT][16]
    const float* __restrict__ bias,    // [COUT]
    __bf16* __restrict__ out_bf,       // [2][65536][COUT]  (RELU path)
    float* __restrict__ out_f)         // [2][COUT][65536]  (else)
{
    __shared__ uint4 tile4[340 * 8];   // 10 rows x 34 wp x 8 chunks(16B), swizzled

    const int tid  = threadIdx.x;
    const int lane = tid & 63;
    const int l31  = lane & 31;
    const int hl   = lane >> 5;
    const int wv   = tid >> 6;
    const int gmi  = wv >> 1;          // m wave-row: 0..1
    const int gni  = wv & 1;           // n wave-col: 0..1

    // grid: vg(2b) | u(4b) | t(2b) | nb(1b)  -> 512 blocks
    const int bid = blockIdx.x;
    const int vg = bid & 3;
    const int u  = (bid >> 2) & 15;
    const int t  = (bid >> 6) & 3;
    const int nb = bid >> 8;
    const int v0 = vg * 8;
    const int pbase = ((t * 16 + u) * 32 + v0) * 32;

    const __bf16* inb = in_t + (size_t)nb * 65536 * CIN;

    f32x16 acc[MT][NT];
    #pragma unroll
    for (int mt = 0; mt < MT; ++mt)
        #pragma unroll
        for (int nt = 0; nt < NT; ++nt)
            #pragma unroll
            for (int i = 0; i < 16; ++i)
                acc[mt][nt][i] = 0.f;

    #pragma unroll 1
    for (int kt = 0; kt < 3; ++kt) {
        const int t_in = t + kt - 1;
        if ((unsigned)t_in >= 4u) continue;            // block-uniform skip
        #pragma unroll 1
        for (int ku = 0; ku < 3; ++ku) {
            const int u_in = u + ku - 1;
            if ((unsigned)u_in >= 16u) continue;       // block-uniform skip
            const int rowbase = (t_in * 16 + u_in) * 1024;
            #pragma unroll 1
            for (int ch = 0; ch < CHALVES; ++ch) {
                __syncthreads();
                // ---- stage 10x34 halo rows x 64 channels, XOR-swizzled ----
                #pragma unroll 1
                for (int idx = tid; idx < 2720; idx += 256) {
                    const int c = idx & 7, pos = idx >> 3;
                    const int r = pos / 34, wp = pos - r * 34;
                    const int v_in = v0 - 1 + r, w_in = wp - 1;
                    uint4 val = make_uint4(0u, 0u, 0u, 0u);
                    if (((unsigned)v_in < 32u) && ((unsigned)w_in < 32u))
                        val = *(const uint4*)(inb +
                              (size_t)(rowbase + v_in * 32 + w_in) * CIN +
                              ch * 64 + c * 8);
                    tile4[pos * 8 + (c ^ (pos & 7))] = val;
                }
                __syncthreads();
                const int tap00 = (kt * 3 + ku) * 3;
                #pragma unroll 1
                for (int kv = 0; kv < 3; ++kv) {
                    #pragma unroll
                    for (int kw = 0; kw < 3; ++kw) {
                        const int tap = (tap00 + kv) * 3 + kw;
                        const __bf16* bbase = wt +
                            ((size_t)tap * (CIN / 16) + ch * 4) * (COUT * 16);
                        #pragma unroll
                        for (int ks = 0; ks < 4; ++ks) {
                            bf16x8 af[MT];
                            #pragma unroll
                            for (int mt = 0; mt < MT; ++mt) {
                                const int pos = (gmi * MT + mt + kv) * 34 + l31 + kw;
                                af[mt] = *(const bf16x8*)&tile4[pos * 8 +
                                         ((ks * 2 + hl) ^ (pos & 7))];
                            }
                            bf16x8 bfv[NT];
                            #pragma unroll
                            for (int nt = 0; nt < NT; ++nt) {
                                const int o = (gni * NT + nt) * 32 + l31;
                                bfv[nt] = *(const bf16x8*)(bbase +
                                          (size_t)ks * (COUT * 16) + o * 16 + hl * 8);
                            }
                            #pragma unroll
                            for (int mt = 0; mt < MT; ++mt)
                                #pragma unroll
                                for (int nt = 0; nt < NT; ++nt)
                                    acc[mt][nt] = __builtin_amdgcn_mfma_f32_32x32x16_bf16(
                                        af[mt], bfv[nt], acc[mt][nt], 0, 0, 0);
                        }
                    }
                }
            }
        }
    }

    // ---- epilogue: C/D 32x32: col = lane&31, row = (reg&3) + 8*(reg>>2) + 4*hl ----
    #pragma unroll
    for (int nt = 0; nt < NT; ++nt) {
        const int o = (gni * NT + nt) * 32 + l31;
        const float bv = bias[o];
        #pragma unroll
        for (int mt = 0; mt < MT; ++mt) {
            const int pb = pbase + (gmi * MT + mt) * 32;
            if constexpr (RELU) {
                #pragma unroll
                for (int rg = 0; rg < 4; ++rg)
                    #pragma unroll
                    for (int j = 0; j < 4; ++j) {
                        float v = acc[mt][nt][rg * 4 + j] + bv;
                        v = v > 0.f ? v : 0.f;
                        const int p = pb + j + 8 * rg + 4 * hl;
                        out_bf[(size_t)(nb * 65536 + p) * COUT + o] = (__bf16)v;
                    }
            } else {
                #pragma unroll
                for (int rg = 0; rg < 4; ++rg) {
                    f32x4 s;
                    #pragma unroll
                    for (int j = 0; j < 4; ++j)
                        s[j] = acc[mt][nt][rg * 4 + j] + bv;
                    const int p = pb + 8 * rg + 4 * hl;
                    *(f32x4*)(out_f + ((size_t)nb * COUT + o) * 65536 + p) = s;
                }
            }
        }
    }
}

extern "C" void kernel_launch(void* const* d_in, const int* in_sizes, int n_in,
                              void* d_out, int out_size, void* d_ws, size_t ws_size,
                              hipStream_t stream) {
    const float* x  = (const float*)d_in[0];
    const float* w1 = (const float*)d_in[1];
    const float* b1 = (const float*)d_in[2];
    const float* w2 = (const float*)d_in[3];
    const float* b2 = (const float*)d_in[4];
    float* out = (float*)d_out;

    char* ws = (char*)d_ws;
    __bf16* x_t = (__bf16*)ws;                               // 16,777,216 B
    __bf16* h_t = (__bf16*)(ws + 16777216);                  // 33,554,432 B
    __bf16* w1t = (__bf16*)(ws + 16777216 + 33554432);       //  1,327,104 B
    __bf16* w2t = (__bf16*)(ws + 16777216 + 33554432 + 1327104);

    cvt_x<<<dim3(1024, 2), 256, 0, stream>>>(x, x_t);
    cvt_w<64><<<32, 256, 0, stream>>>(w1, w1t);
    cvt_w<128><<<32, 256, 0, stream>>>(w2, w2t);

    // conv1: wave 128x64 (MT=4, NT=2), N=128, full 64ch per stage, relu->bf16 ch-last
    conv4d_mfma<64, 128, 4, 2, 1, true><<<512, 256, 0, stream>>>(x_t, w1t, b1, h_t, nullptr);
    // conv2: wave 128x32 (MT=4, NT=1), N=64, two 64ch halves per stage, fp32 planar out
    conv4d_mfma<128, 64, 4, 1, 2, false><<<512, 256, 0, stream>>>(h_t, w2t, b2, nullptr, out);
}

// Round 4
// 402.843 us; speedup vs baseline: 1.8472x; 1.1324x over previous
//
#include <hip/hip_runtime.h>

// ConvMlp4d: conv4d(64->128) + bias + relu -> conv4d(128->64) + bias.
// R4: XCD-aware block swizzle (per-XCD L2-resident staging), async
// global_load_lds(16B) staging with zero-page halo redirect, linear
// chunk-plane LDS layout [row][chunk8][wp34] (conflict-free, all-immediate
// ds offsets), kv-reuse (each A-frag drives all 3 kv taps).
//   ws: x_t bf16 [2][65536][64] | h_t bf16 [2][65536][128]
//       w1t bf16 [81][4][128][16] | w2t bf16 [81][8][64][16] | zeropad 256B

using bf16x8 = __attribute__((ext_vector_type(8))) __bf16;
using f32x16 = __attribute__((ext_vector_type(16))) float;
using f32x4  = __attribute__((ext_vector_type(4))) float;

typedef __attribute__((address_space(1))) const void as1_void;
typedef __attribute__((address_space(3))) void as3_void;
__device__ __forceinline__ void gload_lds16(const void* g, void* l) {
    __builtin_amdgcn_global_load_lds((as1_void*)g, (as3_void*)l, 16, 0, 0);
}

// ---------------- prep: x (2,64,65536) f32 -> x_t (2,65536,64) bf16 ----------------
__global__ __launch_bounds__(256) void cvt_x(const float* __restrict__ x,
                                             __bf16* __restrict__ x_t) {
    __shared__ float lt[64][65];
    const int nb = blockIdx.y;
    const int p0 = blockIdx.x * 64;
    const float* src = x + (size_t)nb * 64 * 65536;
    __bf16* dst = x_t + (size_t)nb * 65536 * 64;
    #pragma unroll
    for (int i = 0; i < 16; ++i) {
        int idx = i * 256 + threadIdx.x;
        int c = idx >> 6, p = idx & 63;
        lt[c][p] = src[(size_t)c * 65536 + p0 + p];
    }
    __syncthreads();
    #pragma unroll
    for (int i = 0; i < 16; ++i) {
        int idx = i * 256 + threadIdx.x;
        int p = idx >> 6, c = idx & 63;
        dst[(size_t)(p0 + p) * 64 + c] = (__bf16)lt[c][p];
    }
}

// ------- prep: w (O,CIN,81) f32 -> wt [81][CIN/16][COUT][16] bf16 (frag-coalesced) --
template <int CIN>
__global__ __launch_bounds__(256) void cvt_w(const float* __restrict__ w,
                                             __bf16* __restrict__ wt) {
    constexpr int LOG = (CIN == 64) ? 6 : 7;
    constexpr int COUT = 8192 / CIN;
    int oc = blockIdx.x * 256 + threadIdx.x;          // o*CIN + c
    if (oc >= 8192) return;
    const int o = oc >> LOG, c = oc & (CIN - 1);
    const int kg = c >> 4, cl = c & 15;
    const float* src = w + (size_t)oc * 81;
    #pragma unroll 1
    for (int tap = 0; tap < 81; ++tap)
        wt[(((size_t)tap * (CIN / 16) + kg) * COUT + o) * 16 + cl] = (__bf16)src[tap];
}

// ---------------- fused conv4d (implicit GEMM, 32x32x16 bf16 MFMA) -----------------
// Block 256 thr = 4 waves (2m x 2n). Block tile M=256 (v-span 8), N=2*NT*32.
// LDS tile: [row 0..9(+slack)][chunk 0..7][wp 0..33] x 16B; 49152 B.
// A-read addr = lane_base(kw) + imm(r,ks) -> zero per-iter VALU, conflict-free.
// Staging: 12 global_load_lds(16B)/wave/stage, per-lane offsets precomputed,
// OOB lanes read a zeroed page. Grid swizzle: xcd = bid&7 owns u = xcd*2+{0,1}.
template <int CIN, int COUT, int NT, int CHALVES, bool RELU>
__global__ __launch_bounds__(256, 2) void conv4d_mfma(
    const __bf16* __restrict__ in_t,   // [2][65536][CIN] channels-last
    const __bf16* __restrict__ wt,     // [81][CIN/16][COUT][16]
    const float* __restrict__ bias,    // [COUT]
    __bf16* __restrict__ out_bf,       // [2][65536][COUT]  (RELU path)
    float* __restrict__ out_f,         // [2][COUT][65536]  (else)
    const __bf16* __restrict__ zp)     // 256B zero page
{
    constexpr int KST = CIN / 16;
    __shared__ __bf16 tile[3072 * 8];  // 49152 B

    const int tid  = threadIdx.x;
    const int lane = tid & 63;
    const int l31  = lane & 31;
    const int hl   = lane >> 5;
    const int wv   = tid >> 6;
    const int gmi  = wv >> 1;          // m wave-row 0..1
    const int gni  = wv & 1;           // n wave-col 0..1

    // grid swizzle: xcd(3b) | ulo(1b) | vg(2b) | t(2b) | nb(1b); u = xcd*2+ulo
    const int bid = blockIdx.x;
    const int xcd = bid & 7;
    const int s   = bid >> 3;
    const int u   = xcd * 2 + (s & 1);
    const int vg  = (s >> 1) & 3;
    const int t   = (s >> 3) & 3;
    const int nb  = (s >> 5) & 1;
    const int v0  = vg * 8;
    const int pbase = ((t * 16 + u) * 32 + v0) * 32;

    const __bf16* inb = in_t + (size_t)nb * 65536 * CIN;

    // ---- staging offsets, precomputed once (per-lane) ----
    int goff[12];
    #pragma unroll
    for (int it = 0; it < 12; ++it) {
        const int idx = it * 256 + tid;            // 16B-chunk index
        const int row = idx / 272;                 // [row][chunk][wp]
        const int rem = idx - row * 272;
        const int chunk = rem / 34;
        const int wp  = rem - chunk * 34;
        const int v_in = v0 - 1 + row;
        const int w_in = wp - 1;
        const bool ok = (row < 10) && ((unsigned)v_in < 32u) && ((unsigned)w_in < 32u);
        goff[it] = ok ? ((v_in * 32 + w_in) * CIN + chunk * 8) : -1;
    }

    // A-frag lane base pointers (16B units): idx = row*272 + (ks*2+hl)*34 + l31+kw
    const bf16x8* tile16 = (const bf16x8*)tile;
    const bf16x8* abase[3];
    #pragma unroll
    for (int kw = 0; kw < 3; ++kw)
        abase[kw] = tile16 + (gmi * 1088 + hl * 34 + l31 + kw);

    // B lane pointers (elements): o = (gni*NT+nt)*32 + l31; + hl*8 within 16ch
    const __bf16* wlane[NT];
    #pragma unroll
    for (int nt = 0; nt < NT; ++nt)
        wlane[nt] = wt + ((gni * NT + nt) * 32 + l31) * 16 + hl * 8;

    f32x16 acc[4][NT];
    #pragma unroll
    for (int mt = 0; mt < 4; ++mt)
        #pragma unroll
        for (int nt = 0; nt < NT; ++nt)
            #pragma unroll
            for (int i = 0; i < 16; ++i)
                acc[mt][nt][i] = 0.f;

    #pragma unroll 1
    for (int kt = 0; kt < 3; ++kt) {
        const int t_in = t + kt - 1;
        if ((unsigned)t_in >= 4u) continue;
        #pragma unroll 1
        for (int ku = 0; ku < 3; ++ku) {
            const int u_in = u + ku - 1;
            if ((unsigned)u_in >= 16u) continue;
            const int tapbase = (kt * 3 + ku) * 9;
            const __bf16* gstage0 = inb + (size_t)((t_in * 16 + u_in) * 1024) * CIN;
            #pragma unroll 1
            for (int ch = 0; ch < CHALVES; ++ch) {
                const __bf16* gstage = gstage0 + ch * 64;
                __syncthreads();                      // prior reads done
                #pragma unroll
                for (int it = 0; it < 12; ++it) {
                    const __bf16* gp = (goff[it] >= 0) ? (gstage + goff[it]) : zp;
                    char* lp = ((char*)tile) + it * 4096 + wv * 1024;
                    gload_lds16(gp, lp);
                }
                __syncthreads();                      // staged data visible
                #pragma unroll
                for (int ks = 0; ks < 4; ++ks) {
                    const int ksg = ch * 4 + ks;
                    // A-frags for this ks: 6 rows x 3 kw, immediate ds offsets
                    bf16x8 af[6][3];
                    #pragma unroll
                    for (int r = 0; r < 6; ++r)
                        #pragma unroll
                        for (int kw = 0; kw < 3; ++kw)
                            af[r][kw] = abase[kw][r * 272 + ks * 68];
                    #pragma unroll
                    for (int kv = 0; kv < 3; ++kv)
                        #pragma unroll
                        for (int kw = 0; kw < 3; ++kw) {
                            const size_t wo =
                                ((size_t)(tapbase + kv * 3 + kw) * KST + ksg) *
                                (COUT * 16);
                            bf16x8 bv[NT];
                            #pragma unroll
                            for (int nt = 0; nt < NT; ++nt)
                                bv[nt] = *(const bf16x8*)(wlane[nt] + wo);
                            #pragma unroll
                            for (int r = kv; r < kv + 4; ++r)
                                #pragma unroll
                                for (int nt = 0; nt < NT; ++nt)
                                    acc[r - kv][nt] =
                                        __builtin_amdgcn_mfma_f32_32x32x16_bf16(
                                            af[r][kw], bv[nt], acc[r - kv][nt],
                                            0, 0, 0);
                        }
                }
            }
        }
    }

    // ---- epilogue: C/D 32x32: col = lane&31, row = (reg&3) + 8*(reg>>2) + 4*hl ----
    #pragma unroll
    for (int nt = 0; nt < NT; ++nt) {
        const int o = (gni * NT + nt) * 32 + l31;
        const float bv = bias[o];
        #pragma unroll
        for (int mt = 0; mt < 4; ++mt) {
            const int pb = pbase + (gmi * 4 + mt) * 32;
            if constexpr (RELU) {
                #pragma unroll
                for (int rg = 0; rg < 4; ++rg)
                    #pragma unroll
                    for (int j = 0; j < 4; ++j) {
                        float v = acc[mt][nt][rg * 4 + j] + bv;
                        v = v > 0.f ? v : 0.f;
                        const int p = pb + j + 8 * rg + 4 * hl;
                        out_bf[(size_t)(nb * 65536 + p) * COUT + o] = (__bf16)v;
                    }
            } else {
                #pragma unroll
                for (int rg = 0; rg < 4; ++rg) {
                    f32x4 sv;
                    #pragma unroll
                    for (int j = 0; j < 4; ++j)
                        sv[j] = acc[mt][nt][rg * 4 + j] + bv;
                    const int p = pb + 8 * rg + 4 * hl;
                    *(f32x4*)(out_f + ((size_t)nb * COUT + o) * 65536 + p) = sv;
                }
            }
        }
    }
}

extern "C" void kernel_launch(void* const* d_in, const int* in_sizes, int n_in,
                              void* d_out, int out_size, void* d_ws, size_t ws_size,
                              hipStream_t stream) {
    const float* x  = (const float*)d_in[0];
    const float* w1 = (const float*)d_in[1];
    const float* b1 = (const float*)d_in[2];
    const float* w2 = (const float*)d_in[3];
    const float* b2 = (const float*)d_in[4];
    float* out = (float*)d_out;

    char* ws = (char*)d_ws;
    __bf16* x_t = (__bf16*)ws;                               // 16,777,216 B
    __bf16* h_t = (__bf16*)(ws + 16777216);                  // 33,554,432 B
    __bf16* w1t = (__bf16*)(ws + 50331648);                  //  1,327,104 B
    __bf16* w2t = (__bf16*)(ws + 51658752);                  //  1,327,104 B
    __bf16* zp  = (__bf16*)(ws + 52985856);                  //        256 B

    hipMemsetAsync(zp, 0, 256, stream);
    cvt_x<<<dim3(1024, 2), 256, 0, stream>>>(x, x_t);
    cvt_w<64><<<32, 256, 0, stream>>>(w1, w1t);
    cvt_w<128><<<32, 256, 0, stream>>>(w2, w2t);

    // conv1: wave 128x64 (NT=2), full 64ch per stage, relu -> bf16 channels-last
    conv4d_mfma<64, 128, 2, 1, true><<<512, 256, 0, stream>>>(x_t, w1t, b1, h_t,
                                                              nullptr, zp);
    // conv2: wave 128x32 (NT=1), two 64ch halves per stage, fp32 planar out
    conv4d_mfma<128, 64, 1, 2, false><<<512, 256, 0, stream>>>(h_t, w2t, b2, nullptr,
                                                               out, zp);
}